// Round 5
// baseline (1434.625 us; speedup 1.0000x reference)
//
#include <hip/hip_runtime.h>
#include <hip/hip_bf16.h>

using bf16 = __hip_bfloat16;
typedef __attribute__((ext_vector_type(8))) short short8;
typedef __attribute__((ext_vector_type(4))) float floatx4;

__device__ __forceinline__ float b2f(bf16 x) { return __bfloat162float(x); }
__device__ __forceinline__ bf16  f2b(float x) { return __float2bfloat16(x); }
// dual-dtype raw-input load: fp32 or bf16 depending on runtime flag
__device__ __forceinline__ float ld(const void* p, size_t i, int f32) {
  return f32 ? ((const float*)p)[i] : b2f(((const bf16*)p)[i]);
}

// ---------------- dtype detector: fp32 inputs have garbage-exponent low halves ----------------
__global__ void detect_kernel(const void* q, int* flag) {
  if (threadIdx.x == 0) {
    const unsigned short* u = (const unsigned short*)q;
    int f = 0;
    for (int i = 0; i < 128; i++) {
      unsigned e = (u[i] >> 7) & 0xFF;
      if (e >= 141) f = 1;
    }
    *flag = f;
  }
}

// ---------------- feat transpose: (6,128,h,w) -> (6,h,w,128) ----------------
__global__ __launch_bounds__(256) void tfeat_kernel(const void* __restrict__ in,
                                                    bf16* __restrict__ out, int h, int w,
                                                    const int* flag) {
  int f = *flag;
  int idx = blockIdx.x * 256 + threadIdx.x;  // ((n*h+y)*w+x)*128 + c
  int c = idx & 127;
  int rest = idx >> 7;
  int x = rest % w;
  int rest2 = rest / w;
  int y = rest2 % h;
  int n = rest2 / h;
  out[idx] = f2b(ld(in, (size_t)((n * 128 + c) * h + y) * w + x, f));
}

// ---------------- weight transpose: [K,N] -> [N,K] ----------------
__global__ __launch_bounds__(256) void tw_kernel(const void* __restrict__ in,
                                                 bf16* __restrict__ out, int K, int N,
                                                 const int* flag) {
  int f = *flag;
  int idx = blockIdx.x * 256 + threadIdx.x;
  if (idx >= K * N) return;
  int n = idx % N, k = idx / N;
  out[n * K + k] = f2b(ld(in, idx, f));
}

// ---------------- sampling: one block per query; ALL geometry in fp32 ----------------
__global__ __launch_bounds__(256) void sample_kernel(
    const void* __restrict__ query,      // [Q,8,128] raw
    const void* __restrict__ query_pos,  // [8,Q,3] raw
    const void* __restrict__ l2i,        // [6,4,4] raw
    const void* __restrict__ W_sw,       // [128,16] raw
    const void* __restrict__ b_sw,       // [16] raw
    const bf16* __restrict__ ft,         // channel-last feats (bf16 ws)
    bf16* __restrict__ X,                // [Q,1024]
    const int* flag) {
  const int f32 = *flag;
  const int q = blockIdx.x;
  const int t = threadIdx.x;
  __shared__ float qs[1024];
  __shared__ float wswS[2048];
  __shared__ float qpL[24];
  __shared__ float lgL[128];
  __shared__ float swL[128];
  __shared__ float uL[8], vL[8];
  __shared__ int camL[8], avL[8];

  for (int i = t; i < 1024; i += 256) qs[i] = ld(query, (size_t)q * 1024 + i, f32);
  for (int i = t; i < 2048; i += 256) wswS[i] = ld(W_sw, i, f32);
  if (t < 24) {
    int z = t / 3, i = t - z * 3;
    qpL[t] = ld(query_pos, ((size_t)z * 40000 + q) * 3 + i, f32);
  }
  __syncthreads();

  if (t < 128) {
    int p = t >> 4, gl = t & 15;
    float s = ld(b_sw, gl, f32);
    const float* qp_ = &qs[p * 128];
    for (int k = 0; k < 128; k++) s += qp_[k] * wswS[k * 16 + gl];
    lgL[t] = s;
  } else if (t < 136) {
    int p = t - 128;
    float px = qpL[p * 3 + 0] * 100.f - 50.f;
    float py = qpL[p * 3 + 1] * 100.f - 50.f;
    float pz = qpL[p * 3 + 2] * 8.f - 4.f;
    int cam = 0, found = 0;
    float usel = 0.f, vsel = 0.f;
    for (int n = 0; n < 6; n++) {
      float m[12];
      #pragma unroll
      for (int i = 0; i < 12; i++) m[i] = ld(l2i, n * 16 + i, f32);
      float c0 = m[0] * px + m[1] * py + m[2] * pz + m[3];
      float c1 = m[4] * px + m[5] * py + m[6] * pz + m[7];
      float c2 = m[8] * px + m[9] * py + m[10] * pz + m[11];
      float d = fmaxf(c2, 1e-6f);
      float u = (c0 / d) / 480.f;
      float v = (c1 / d) / 224.f;
      int valid = (c2 > 1e-6f) && (u > 0.f) && (u < 1.f) && (v > 0.f) && (v < 1.f);
      if (valid && !found) { found = 1; cam = n; usel = u; vsel = v; }
    }
    uL[p] = usel; vL[p] = vsel; camL[p] = cam; avL[p] = found;
  }
  __syncthreads();

  if (t < 32) {
    int base = t * 4;
    float a0 = lgL[base], a1 = lgL[base + 1], a2 = lgL[base + 2], a3 = lgL[base + 3];
    float mx = fmaxf(fmaxf(a0, a1), fmaxf(a2, a3));
    float e0 = expf(a0 - mx), e1 = expf(a1 - mx), e2 = expf(a2 - mx), e3 = expf(a3 - mx);
    float inv = 1.f / (e0 + e1 + e2 + e3);
    swL[base] = e0 * inv; swL[base + 1] = e1 * inv;
    swL[base + 2] = e2 * inv; swL[base + 3] = e3 * inv;
  }
  __syncthreads();

  const int LH[4] = {56, 28, 14, 7}, LW[4] = {120, 60, 30, 15};
  const size_t FOFF[4] = {0, 5160960, 6451200, 6773760};
  const int e = t & 127;
  const int g = e >> 5;
  for (int it = 0; it < 4; it++) {
    int p = it * 2 + (t >> 7);
    float res = 0.f;
    if (avL[p]) {
      float u = uL[p], v = vL[p];
      int cam = camL[p];
      #pragma unroll
      for (int l = 0; l < 4; l++) {
        int h = LH[l], w = LW[l];
        const bf16* fp = ft + FOFF[l] + (size_t)cam * h * w * 128;
        float x = u * w - 0.5f, y = v * h - 0.5f;
        float x0f = floorf(x), y0f = floorf(y);
        float wx = x - x0f, wy = y - y0f;
        int x0 = (int)x0f, y0 = (int)y0f;
        bool xi0 = (x0 >= 0) && (x0 < w), xi1 = (x0 + 1 >= 0) && (x0 + 1 < w);
        bool yi0 = (y0 >= 0) && (y0 < h), yi1 = (y0 + 1 >= 0) && (y0 + 1 < h);
        float v00 = 0.f, v01 = 0.f, v10 = 0.f, v11 = 0.f;
        if (yi0 && xi0) v00 = b2f(fp[((size_t)y0 * w + x0) * 128 + e]);
        if (yi0 && xi1) v01 = b2f(fp[((size_t)y0 * w + x0 + 1) * 128 + e]);
        if (yi1 && xi0) v10 = b2f(fp[((size_t)(y0 + 1) * w + x0) * 128 + e]);
        if (yi1 && xi1) v11 = b2f(fp[((size_t)(y0 + 1) * w + x0 + 1) * 128 + e]);
        float bil = v00 * (1.f - wx) * (1.f - wy) + v01 * wx * (1.f - wy)
                  + v10 * (1.f - wx) * wy + v11 * wx * wy;
        res += swL[p * 16 + g * 4 + l] * bil;
      }
    }
    X[(size_t)q * 1024 + p * 128 + e] = f2b(res);
  }
}

// ---------------- bf16 MFMA GEMM: C = relu?(A[M,K] @ Bt[N,K]^T + bias) ----------------
// trans_out: write fp32 transposed [N,M] to Cf; else bf16 row-major [M,N] to Cd.
__global__ __launch_bounds__(256) void gemm_bt(
    const bf16* __restrict__ A, const bf16* __restrict__ Bt, const void* __restrict__ bias,
    bf16* __restrict__ Cd, float* __restrict__ Cf,
    int M, int N, int K, int relu, int trans_out, const int* flag) {
  __shared__ bf16 As[64 * 40];
  __shared__ bf16 Bs[64 * 40];
  const int f32 = *flag;
  const int t = threadIdx.x;
  const int bm = blockIdx.x * 64;
  const int bn = blockIdx.y * 64;
  const int wv = t >> 6, lane = t & 63;
  const int wm = (wv >> 1) * 32, wn = (wv & 1) * 32;
  const int quad = lane >> 4, l15 = lane & 15;
  const int srow = t >> 2, scol = (t & 3) * 8;
  floatx4 acc[2][2] = {};
  for (int k0 = 0; k0 < K; k0 += 32) {
    *(uint4*)(&As[srow * 40 + scol]) = *(const uint4*)(&A[(size_t)(bm + srow) * K + k0 + scol]);
    *(uint4*)(&Bs[srow * 40 + scol]) = *(const uint4*)(&Bt[(size_t)(bn + srow) * K + k0 + scol]);
    __syncthreads();
    short8 af[2], bfr[2];
    af[0]  = *(const short8*)(&As[(wm + l15) * 40 + quad * 8]);
    af[1]  = *(const short8*)(&As[(wm + 16 + l15) * 40 + quad * 8]);
    bfr[0] = *(const short8*)(&Bs[(wn + l15) * 40 + quad * 8]);
    bfr[1] = *(const short8*)(&Bs[(wn + 16 + l15) * 40 + quad * 8]);
    #pragma unroll
    for (int mi = 0; mi < 2; mi++)
      #pragma unroll
      for (int ni = 0; ni < 2; ni++)
        acc[mi][ni] = __builtin_amdgcn_mfma_f32_16x16x32_bf16(af[mi], bfr[ni], acc[mi][ni], 0, 0, 0);
    __syncthreads();
  }
  #pragma unroll
  for (int mi = 0; mi < 2; mi++)
    #pragma unroll
    for (int ni = 0; ni < 2; ni++) {
      int gn = bn + wn + ni * 16 + l15;
      float bv = ld(bias, gn, f32);
      #pragma unroll
      for (int r = 0; r < 4; r++) {
        int gm = bm + wm + mi * 16 + quad * 4 + r;
        float v = acc[mi][ni][r] + bv;
        if (relu) v = fmaxf(v, 0.f);
        if (trans_out) Cf[(size_t)gn * M + gm] = v;       // final layer: fp32 [E,Q]
        else           Cd[(size_t)gm * N + gn] = f2b(v);
      }
    }
}

// ---------------- pos_emb GEMM: X[q*8+z][e] += MLP(query_pos)[e] ----------------
__global__ __launch_bounds__(256) void gemm_pe(
    const void* __restrict__ query_pos, const void* __restrict__ pe_w1,
    const void* __restrict__ pe_b1, const void* __restrict__ pe_b2,
    const bf16* __restrict__ pw2t, bf16* __restrict__ X, const int* flag) {
  __shared__ bf16 As[64 * 40];
  __shared__ bf16 Bs[64 * 40];
  __shared__ float qpS[64 * 3];
  const int f32 = *flag;
  const int t = threadIdx.x;
  const int bm = blockIdx.x * 64;
  const int bn = blockIdx.y * 64;
  const int wv = t >> 6, lane = t & 63;
  const int wm = (wv >> 1) * 32, wn = (wv & 1) * 32;
  const int quad = lane >> 4, l15 = lane & 15;
  const int srow = t >> 2, scol = (t & 3) * 8;
  if (t < 64) {
    int r = bm + t, qq = r >> 3, zz = r & 7;
    #pragma unroll
    for (int i = 0; i < 3; i++)
      qpS[t * 3 + i] = ld(query_pos, ((size_t)zz * 40000 + qq) * 3 + i, f32);
  }
  __syncthreads();
  floatx4 acc[2][2] = {};
  for (int k0 = 0; k0 < 256; k0 += 32) {
    float a0 = qpS[srow * 3], a1 = qpS[srow * 3 + 1], a2 = qpS[srow * 3 + 2];
    #pragma unroll
    for (int j = 0; j < 8; j++) {
      int k = k0 + scol + j;
      float h = a0 * ld(pe_w1, k, f32) + a1 * ld(pe_w1, 256 + k, f32)
              + a2 * ld(pe_w1, 512 + k, f32) + ld(pe_b1, k, f32);
      As[srow * 40 + scol + j] = f2b(fmaxf(h, 0.f));
    }
    *(uint4*)(&Bs[srow * 40 + scol]) = *(const uint4*)(&pw2t[(size_t)(bn + srow) * 256 + k0 + scol]);
    __syncthreads();
    short8 af[2], bfr[2];
    af[0]  = *(const short8*)(&As[(wm + l15) * 40 + quad * 8]);
    af[1]  = *(const short8*)(&As[(wm + 16 + l15) * 40 + quad * 8]);
    bfr[0] = *(const short8*)(&Bs[(wn + l15) * 40 + quad * 8]);
    bfr[1] = *(const short8*)(&Bs[(wn + 16 + l15) * 40 + quad * 8]);
    #pragma unroll
    for (int mi = 0; mi < 2; mi++)
      #pragma unroll
      for (int ni = 0; ni < 2; ni++)
        acc[mi][ni] = __builtin_amdgcn_mfma_f32_16x16x32_bf16(af[mi], bfr[ni], acc[mi][ni], 0, 0, 0);
    __syncthreads();
  }
  #pragma unroll
  for (int mi = 0; mi < 2; mi++)
    #pragma unroll
    for (int ni = 0; ni < 2; ni++) {
      int gn = bn + wn + ni * 16 + l15;
      float bv = ld(pe_b2, gn, f32);
      #pragma unroll
      for (int r = 0; r < 4; r++) {
        int gm = bm + wm + mi * 16 + quad * 4 + r;
        size_t off = (size_t)gm * 128 + gn;
        X[off] = f2b(acc[mi][ni][r] + bv + b2f(X[off]));
      }
    }
}

extern "C" void kernel_launch(void* const* d_in, const int* in_sizes, int n_in,
                              void* d_out, int out_size, void* d_ws, size_t ws_size,
                              hipStream_t stream) {
  int* flag = (int*)d_ws;
  bf16* ws = (bf16*)d_ws;
  bf16* ft   = ws + 5760;                // 6,854,400
  bf16* wt1  = ws + 6860160;             // 512x1024
  bf16* wt2  = ws + 7384448;             // 512x512
  bf16* wt3  = ws + 7646592;             // 512x512
  bf16* wt4  = ws + 7908736;             // 128x512
  bf16* pw2t = ws + 7974272;             // 128x256
  bf16* X    = ws + 8007040;             // 40000x1024
  bf16* Ha   = ws + 48967040;            // 40000x512   (ws total ~139 MB)
  bf16* Hb   = X;                        // alias: X dead after layer-1 GEMM

  detect_kernel<<<1, 64, 0, stream>>>(d_in[4], flag);

  tfeat_kernel<<<20160, 256, 0, stream>>>(d_in[0], ft, 56, 120, flag);
  tfeat_kernel<<<5040, 256, 0, stream>>>(d_in[1], ft + 5160960, 28, 60, flag);
  tfeat_kernel<<<1260, 256, 0, stream>>>(d_in[2], ft + 6451200, 14, 30, flag);
  tfeat_kernel<<<315, 256, 0, stream>>>(d_in[3], ft + 6773760, 7, 15, flag);
  tw_kernel<<<2048, 256, 0, stream>>>(d_in[13], wt1, 1024, 512, flag);
  tw_kernel<<<1024, 256, 0, stream>>>(d_in[15], wt2, 512, 512, flag);
  tw_kernel<<<1024, 256, 0, stream>>>(d_in[17], wt3, 512, 512, flag);
  tw_kernel<<<256, 256, 0, stream>>>(d_in[19], wt4, 512, 128, flag);
  tw_kernel<<<128, 256, 0, stream>>>(d_in[11], pw2t, 256, 128, flag);

  sample_kernel<<<40000, 256, 0, stream>>>(d_in[4], d_in[5], d_in[6], d_in[7], d_in[8],
                                           ft, X, flag);
  gemm_pe<<<dim3(5000, 2), 256, 0, stream>>>(d_in[5], d_in[9], d_in[10], d_in[12],
                                             pw2t, X, flag);

  gemm_bt<<<dim3(625, 8), 256, 0, stream>>>(X,  wt1, d_in[14], Ha, nullptr, 40000, 512, 1024, 1, 0, flag);
  gemm_bt<<<dim3(625, 8), 256, 0, stream>>>(Ha, wt2, d_in[16], Hb, nullptr, 40000, 512, 512, 1, 0, flag);
  gemm_bt<<<dim3(625, 8), 256, 0, stream>>>(Hb, wt3, d_in[18], Ha, nullptr, 40000, 512, 512, 1, 0, flag);
  gemm_bt<<<dim3(625, 2), 256, 0, stream>>>(Ha, wt4, d_in[20], nullptr, (float*)d_out, 40000, 128, 512, 0, 1, flag);
}

// Round 6
// 1273.757 us; speedup vs baseline: 1.1263x; 1.1263x over previous
//
#include <hip/hip_runtime.h>
#include <hip/hip_bf16.h>

using bf16 = __hip_bfloat16;
typedef __attribute__((ext_vector_type(8))) short short8;
typedef __attribute__((ext_vector_type(4))) float floatx4;

__device__ __forceinline__ float b2f(bf16 x) { return __bfloat162float(x); }
__device__ __forceinline__ bf16  f2b(float x) { return __float2bfloat16(x); }
__device__ __forceinline__ float u2f(unsigned x) { return __uint_as_float(x); }
// dual-dtype raw-input load: fp32 or bf16 depending on runtime flag
__device__ __forceinline__ float ld(const void* p, size_t i, int f32) {
  return f32 ? ((const float*)p)[i] : b2f(((const bf16*)p)[i]);
}

// ---------------- dtype detector ----------------
__global__ void detect_kernel(const void* q, int* flag) {
  if (threadIdx.x == 0) {
    const unsigned short* u = (const unsigned short*)q;
    int f = 0;
    for (int i = 0; i < 128; i++) {
      unsigned e = (u[i] >> 7) & 0xFF;
      if (e >= 141) f = 1;
    }
    *flag = f;
  }
}

// ---------------- feat transpose: (6,128,h,w) -> (6,h,w,128) ----------------
__global__ __launch_bounds__(256) void tfeat_kernel(const void* __restrict__ in,
                                                    bf16* __restrict__ out, int h, int w,
                                                    const int* flag) {
  int f = *flag;
  int idx = blockIdx.x * 256 + threadIdx.x;
  int c = idx & 127;
  int rest = idx >> 7;
  int x = rest % w;
  int rest2 = rest / w;
  int y = rest2 % h;
  int n = rest2 / h;
  out[idx] = f2b(ld(in, (size_t)((n * 128 + c) * h + y) * w + x, f));
}

// ---------------- weight transpose: [K,N] -> [N,K] ----------------
__global__ __launch_bounds__(256) void tw_kernel(const void* __restrict__ in,
                                                 bf16* __restrict__ out, int K, int N,
                                                 const int* flag) {
  int f = *flag;
  int idx = blockIdx.x * 256 + threadIdx.x;
  if (idx >= K * N) return;
  int n = idx % N, k = idx / N;
  out[n * K + k] = f2b(ld(in, idx, f));
}

// ---------------- S1: logits+softmax+projection, one thread per (q,p) row ----------------
__global__ __launch_bounds__(256) void logit_proj_kernel(
    const void* __restrict__ query,      // [320000,128] raw
    const void* __restrict__ query_pos,  // [8,40000,3] raw
    const void* __restrict__ l2i,        // [6,4,4] raw
    const void* __restrict__ W_sw,       // [128,16] raw
    const void* __restrict__ b_sw,       // [16] raw
    float* __restrict__ swG,             // [320000,16]
    float* __restrict__ uG, float* __restrict__ vG, int* __restrict__ cvG,
    const int* flag) {
  const int f32 = *flag;
  const int t = threadIdx.x;
  const int row0 = blockIdx.x * 256;
  __shared__ float As[256][33];
  __shared__ float wswS[2048];
  __shared__ float bswS[16];
  for (int i = t; i < 2048; i += 256) wswS[i] = ld(W_sw, i, f32);
  if (t < 16) bswS[t] = ld(b_sw, t, f32);
  float acc[16];
  #pragma unroll
  for (int c = 0; c < 16; c++) acc[c] = 0.f;
  for (int k0 = 0; k0 < 128; k0 += 32) {
    __syncthreads();
    for (int i = t; i < 8192; i += 256) {
      int r = i >> 5, kk = i & 31;
      As[r][kk] = ld(query, (size_t)(row0 + r) * 128 + k0 + kk, f32);
    }
    __syncthreads();
    for (int kk = 0; kk < 32; kk++) {
      float a = As[t][kk];
      #pragma unroll
      for (int c = 0; c < 16; c++) acc[c] += a * wswS[(k0 + kk) * 16 + c];
    }
  }
  const int row = row0 + t;
  #pragma unroll
  for (int c = 0; c < 16; c++) acc[c] += bswS[c];
  #pragma unroll
  for (int g = 0; g < 4; g++) {
    float a0 = acc[4 * g], a1 = acc[4 * g + 1], a2 = acc[4 * g + 2], a3 = acc[4 * g + 3];
    float mx = fmaxf(fmaxf(a0, a1), fmaxf(a2, a3));
    float e0 = expf(a0 - mx), e1 = expf(a1 - mx), e2 = expf(a2 - mx), e3 = expf(a3 - mx);
    float inv = 1.f / (e0 + e1 + e2 + e3);
    swG[(size_t)row * 16 + 4 * g]     = e0 * inv;
    swG[(size_t)row * 16 + 4 * g + 1] = e1 * inv;
    swG[(size_t)row * 16 + 4 * g + 2] = e2 * inv;
    swG[(size_t)row * 16 + 4 * g + 3] = e3 * inv;
  }
  // projection
  int q = row >> 3, p = row & 7;
  float q0 = ld(query_pos, ((size_t)p * 40000 + q) * 3 + 0, f32);
  float q1 = ld(query_pos, ((size_t)p * 40000 + q) * 3 + 1, f32);
  float q2 = ld(query_pos, ((size_t)p * 40000 + q) * 3 + 2, f32);
  float px = q0 * 100.f - 50.f;
  float py = q1 * 100.f - 50.f;
  float pz = q2 * 8.f - 4.f;
  int cam = 0, found = 0;
  float usel = 0.f, vsel = 0.f;
  for (int n = 0; n < 6; n++) {
    float m[12];
    #pragma unroll
    for (int i = 0; i < 12; i++) m[i] = ld(l2i, n * 16 + i, f32);
    float c0 = m[0] * px + m[1] * py + m[2] * pz + m[3];
    float c1 = m[4] * px + m[5] * py + m[6] * pz + m[7];
    float c2 = m[8] * px + m[9] * py + m[10] * pz + m[11];
    float d = fmaxf(c2, 1e-6f);
    float u = (c0 / d) / 480.f;
    float v = (c1 / d) / 224.f;
    int valid = (c2 > 1e-6f) && (u > 0.f) && (u < 1.f) && (v > 0.f) && (v < 1.f);
    if (valid && !found) { found = 1; cam = n; usel = u; vsel = v; }
  }
  uG[row] = usel; vG[row] = vsel; cvG[row] = cam | (found << 3);
}

// ---------------- S2: gather, one wave per (q,p) row; lane owns 2 channels ----------------
__global__ __launch_bounds__(256) void gather_kernel(
    const float* __restrict__ swG, const float* __restrict__ uG,
    const float* __restrict__ vG, const int* __restrict__ cvG,
    const bf16* __restrict__ ft, bf16* __restrict__ X) {
  const int t = threadIdx.x;
  const int lane = t & 63;
  const int row = blockIdx.x * 4 + (t >> 6);
  const unsigned* ftU = (const unsigned*)ft;
  unsigned* XU = (unsigned*)X;
  float acc0 = 0.f, acc1 = 0.f;
  int cv = cvG[row];
  if (cv & 8) {
    float u = uG[row], v = vG[row];
    int cam = cv & 7;
    int g = lane >> 4;
    float wl[4];
    #pragma unroll
    for (int l = 0; l < 4; l++) wl[l] = swG[(size_t)row * 16 + g * 4 + l];
    const int LH[4] = {56, 28, 14, 7}, LW[4] = {120, 60, 30, 15};
    const int FOFFU[4] = {0, 2580480, 3225600, 3386880};  // uint-elem offsets
    #pragma unroll
    for (int l = 0; l < 4; l++) {
      int h = LH[l], w = LW[l];
      int base_l = FOFFU[l] + cam * h * w * 64;
      float x = u * w - 0.5f, y = v * h - 0.5f;
      float x0f = floorf(x), y0f = floorf(y);
      float wx = x - x0f, wy = y - y0f;
      int x0 = (int)x0f, y0 = (int)y0f;
      bool xi0 = (x0 >= 0) && (x0 < w), xi1 = (x0 + 1 >= 0) && (x0 + 1 < w);
      bool yi0 = (y0 >= 0) && (y0 < h), yi1 = (y0 + 1 >= 0) && (y0 + 1 < h);
      float b0 = 0.f, b1 = 0.f;
      if (yi0 && xi0) {
        unsigned vv = ftU[base_l + (y0 * w + x0) * 64 + lane];
        float cw = (1.f - wx) * (1.f - wy);
        b0 += u2f(vv << 16) * cw; b1 += u2f(vv & 0xFFFF0000u) * cw;
      }
      if (yi0 && xi1) {
        unsigned vv = ftU[base_l + (y0 * w + x0 + 1) * 64 + lane];
        float cw = wx * (1.f - wy);
        b0 += u2f(vv << 16) * cw; b1 += u2f(vv & 0xFFFF0000u) * cw;
      }
      if (yi1 && xi0) {
        unsigned vv = ftU[base_l + ((y0 + 1) * w + x0) * 64 + lane];
        float cw = (1.f - wx) * wy;
        b0 += u2f(vv << 16) * cw; b1 += u2f(vv & 0xFFFF0000u) * cw;
      }
      if (yi1 && xi1) {
        unsigned vv = ftU[base_l + ((y0 + 1) * w + x0 + 1) * 64 + lane];
        float cw = wx * wy;
        b0 += u2f(vv << 16) * cw; b1 += u2f(vv & 0xFFFF0000u) * cw;
      }
      acc0 += wl[l] * b0; acc1 += wl[l] * b1;
    }
  }
  unsigned lo = (unsigned)(unsigned short)__bfloat16_as_ushort(f2b(acc0));
  unsigned hi = (unsigned)(unsigned short)__bfloat16_as_ushort(f2b(acc1));
  XU[(size_t)row * 64 + lane] = lo | (hi << 16);
}

// ---------------- bf16 MFMA GEMM: C = relu?(A[M,K] @ Bt[N,K]^T + bias) ----------------
__global__ __launch_bounds__(256) void gemm_bt(
    const bf16* __restrict__ A, const bf16* __restrict__ Bt, const void* __restrict__ bias,
    bf16* __restrict__ Cd, float* __restrict__ Cf,
    int M, int N, int K, int relu, int trans_out, const int* flag) {
  __shared__ bf16 As[64 * 40];
  __shared__ bf16 Bs[64 * 40];
  const int f32 = *flag;
  const int t = threadIdx.x;
  const int bm = blockIdx.x * 64;
  const int bn = blockIdx.y * 64;
  const int wv = t >> 6, lane = t & 63;
  const int wm = (wv >> 1) * 32, wn = (wv & 1) * 32;
  const int quad = lane >> 4, l15 = lane & 15;
  const int srow = t >> 2, scol = (t & 3) * 8;
  floatx4 acc[2][2] = {};
  for (int k0 = 0; k0 < K; k0 += 32) {
    *(uint4*)(&As[srow * 40 + scol]) = *(const uint4*)(&A[(size_t)(bm + srow) * K + k0 + scol]);
    *(uint4*)(&Bs[srow * 40 + scol]) = *(const uint4*)(&Bt[(size_t)(bn + srow) * K + k0 + scol]);
    __syncthreads();
    short8 af[2], bfr[2];
    af[0]  = *(const short8*)(&As[(wm + l15) * 40 + quad * 8]);
    af[1]  = *(const short8*)(&As[(wm + 16 + l15) * 40 + quad * 8]);
    bfr[0] = *(const short8*)(&Bs[(wn + l15) * 40 + quad * 8]);
    bfr[1] = *(const short8*)(&Bs[(wn + 16 + l15) * 40 + quad * 8]);
    #pragma unroll
    for (int mi = 0; mi < 2; mi++)
      #pragma unroll
      for (int ni = 0; ni < 2; ni++)
        acc[mi][ni] = __builtin_amdgcn_mfma_f32_16x16x32_bf16(af[mi], bfr[ni], acc[mi][ni], 0, 0, 0);
    __syncthreads();
  }
  #pragma unroll
  for (int mi = 0; mi < 2; mi++)
    #pragma unroll
    for (int ni = 0; ni < 2; ni++) {
      int gn = bn + wn + ni * 16 + l15;
      float bv = ld(bias, gn, f32);
      #pragma unroll
      for (int r = 0; r < 4; r++) {
        int gm = bm + wm + mi * 16 + quad * 4 + r;
        float v = acc[mi][ni][r] + bv;
        if (relu) v = fmaxf(v, 0.f);
        if (trans_out) Cf[(size_t)gn * M + gm] = v;
        else           Cd[(size_t)gm * N + gn] = f2b(v);
      }
    }
}

// ---------------- pos_emb GEMM: X[q*8+z][e] += MLP(query_pos)[e] ----------------
__global__ __launch_bounds__(256) void gemm_pe(
    const void* __restrict__ query_pos, const void* __restrict__ pe_w1,
    const void* __restrict__ pe_b1, const void* __restrict__ pe_b2,
    const bf16* __restrict__ pw2t, bf16* __restrict__ X, const int* flag) {
  __shared__ bf16 As[64 * 40];
  __shared__ bf16 Bs[64 * 40];
  __shared__ float qpS[64 * 3];
  const int f32 = *flag;
  const int t = threadIdx.x;
  const int bm = blockIdx.x * 64;
  const int bn = blockIdx.y * 64;
  const int wv = t >> 6, lane = t & 63;
  const int wm = (wv >> 1) * 32, wn = (wv & 1) * 32;
  const int quad = lane >> 4, l15 = lane & 15;
  const int srow = t >> 2, scol = (t & 3) * 8;
  if (t < 64) {
    int r = bm + t, qq = r >> 3, zz = r & 7;
    #pragma unroll
    for (int i = 0; i < 3; i++)
      qpS[t * 3 + i] = ld(query_pos, ((size_t)zz * 40000 + qq) * 3 + i, f32);
  }
  __syncthreads();
  floatx4 acc[2][2] = {};
  for (int k0 = 0; k0 < 256; k0 += 32) {
    float a0 = qpS[srow * 3], a1 = qpS[srow * 3 + 1], a2 = qpS[srow * 3 + 2];
    #pragma unroll
    for (int j = 0; j < 8; j++) {
      int k = k0 + scol + j;
      float h = a0 * ld(pe_w1, k, f32) + a1 * ld(pe_w1, 256 + k, f32)
              + a2 * ld(pe_w1, 512 + k, f32) + ld(pe_b1, k, f32);
      As[srow * 40 + scol + j] = f2b(fmaxf(h, 0.f));
    }
    *(uint4*)(&Bs[srow * 40 + scol]) = *(const uint4*)(&pw2t[(size_t)(bn + srow) * 256 + k0 + scol]);
    __syncthreads();
    short8 af[2], bfr[2];
    af[0]  = *(const short8*)(&As[(wm + l15) * 40 + quad * 8]);
    af[1]  = *(const short8*)(&As[(wm + 16 + l15) * 40 + quad * 8]);
    bfr[0] = *(const short8*)(&Bs[(wn + l15) * 40 + quad * 8]);
    bfr[1] = *(const short8*)(&Bs[(wn + 16 + l15) * 40 + quad * 8]);
    #pragma unroll
    for (int mi = 0; mi < 2; mi++)
      #pragma unroll
      for (int ni = 0; ni < 2; ni++)
        acc[mi][ni] = __builtin_amdgcn_mfma_f32_16x16x32_bf16(af[mi], bfr[ni], acc[mi][ni], 0, 0, 0);
    __syncthreads();
  }
  #pragma unroll
  for (int mi = 0; mi < 2; mi++)
    #pragma unroll
    for (int ni = 0; ni < 2; ni++) {
      int gn = bn + wn + ni * 16 + l15;
      float bv = ld(pe_b2, gn, f32);
      #pragma unroll
      for (int r = 0; r < 4; r++) {
        int gm = bm + wm + mi * 16 + quad * 4 + r;
        size_t off = (size_t)gm * 128 + gn;
        X[off] = f2b(acc[mi][ni][r] + bv + b2f(X[off]));
      }
    }
}

extern "C" void kernel_launch(void* const* d_in, const int* in_sizes, int n_in,
                              void* d_out, int out_size, void* d_ws, size_t ws_size,
                              hipStream_t stream) {
  int* flag = (int*)d_ws;
  bf16* ws = (bf16*)d_ws;
  bf16* ft   = ws + 5760;                // 6,854,400
  bf16* wt1  = ws + 6860160;             // 512x1024
  bf16* wt2  = ws + 7384448;             // 512x512
  bf16* wt3  = ws + 7646592;             // 512x512
  bf16* wt4  = ws + 7908736;             // 128x512
  bf16* pw2t = ws + 7974272;             // 128x256
  bf16* X    = ws + 8007040;             // 40000x1024
  bf16* Ha   = ws + 48967040;            // 40000x512   (ws total ~139 MB)
  bf16* Hb   = X;                        // alias: X dead after layer-1 GEMM
  // sampling scratch aliased onto Ha (dead until layer-1 GEMM writes it)
  float* swG = (float*)Ha;               // 320000x16 fp32 (10.24M be)
  float* uG  = (float*)(ws + 59207040);  // 320000 fp32
  float* vG  = (float*)(ws + 59847040);  // 320000 fp32
  int*   cvG = (int*)(ws + 60487040);    // 320000 int (ends 61127040 < Ha end)

  detect_kernel<<<1, 64, 0, stream>>>(d_in[4], flag);

  tfeat_kernel<<<20160, 256, 0, stream>>>(d_in[0], ft, 56, 120, flag);
  tfeat_kernel<<<5040, 256, 0, stream>>>(d_in[1], ft + 5160960, 28, 60, flag);
  tfeat_kernel<<<1260, 256, 0, stream>>>(d_in[2], ft + 6451200, 14, 30, flag);
  tfeat_kernel<<<315, 256, 0, stream>>>(d_in[3], ft + 6773760, 7, 15, flag);
  tw_kernel<<<2048, 256, 0, stream>>>(d_in[13], wt1, 1024, 512, flag);
  tw_kernel<<<1024, 256, 0, stream>>>(d_in[15], wt2, 512, 512, flag);
  tw_kernel<<<1024, 256, 0, stream>>>(d_in[17], wt3, 512, 512, flag);
  tw_kernel<<<256, 256, 0, stream>>>(d_in[19], wt4, 512, 128, flag);
  tw_kernel<<<128, 256, 0, stream>>>(d_in[11], pw2t, 256, 128, flag);

  logit_proj_kernel<<<1250, 256, 0, stream>>>(d_in[4], d_in[5], d_in[6], d_in[7], d_in[8],
                                              swG, uG, vG, cvG, flag);
  gather_kernel<<<80000, 256, 0, stream>>>(swG, uG, vG, cvG, ft, X);
  gemm_pe<<<dim3(5000, 2), 256, 0, stream>>>(d_in[5], d_in[9], d_in[10], d_in[12],
                                             pw2t, X, flag);

  gemm_bt<<<dim3(625, 8), 256, 0, stream>>>(X,  wt1, d_in[14], Ha, nullptr, 40000, 512, 1024, 1, 0, flag);
  gemm_bt<<<dim3(625, 8), 256, 0, stream>>>(Ha, wt2, d_in[16], Hb, nullptr, 40000, 512, 512, 1, 0, flag);
  gemm_bt<<<dim3(625, 8), 256, 0, stream>>>(Hb, wt3, d_in[18], Ha, nullptr, 40000, 512, 512, 1, 0, flag);
  gemm_bt<<<dim3(625, 2), 256, 0, stream>>>(Ha, wt4, d_in[20], nullptr, (float*)d_out, 40000, 128, 512, 0, 1, flag);
}